// Round 1
// baseline (181.090 us; speedup 1.0000x reference)
//
#include <hip/hip_runtime.h>
#include <math.h>

#define LL 8192
#define CC 256
#define SS 16
#define GG 256
#define TT 32

#define LOG2E 1.4426950408889634f
#define LN2   0.6931471805599453f

__device__ __forceinline__ float fexp2(float v){ return __builtin_amdgcn_exp2f(v); }
__device__ __forceinline__ float flog2v(float v){ return __builtin_amdgcn_logf(v); }

__device__ __forceinline__ void load16(float* d, const float* __restrict__ p){
    *(float4*)&d[0]  = *(const float4*)&p[0];
    *(float4*)&d[4]  = *(const float4*)&p[4];
    *(float4*)&d[8]  = *(const float4*)&p[8];
    *(float4*)&d[12] = *(const float4*)&p[12];
}

// softplus(z) = max(z,0) + ln2 * log2(1 + 2^(-|z|*log2e))
__device__ __forceinline__ float softplus(float z){
    float t = fexp2(-fabsf(z) * LOG2E);
    return fmaxf(z, 0.f) + LN2 * flog2v(1.f + t);
}

// ---------------- Kernel A: dt = softplus(0.01 + x @ W_dt + b_dt), (L,C) ----
__global__ __launch_bounds__(256) void k_dt(const float* __restrict__ x,
                                            const float* __restrict__ W,
                                            const float* __restrict__ b,
                                            float* __restrict__ dt)
{
    __shared__ float xs[32*260];   // [r][k], stride 260 (mult of 4 -> aligned b128)
    const int tid  = threadIdx.x;
    const int row0 = blockIdx.x * 32;
    #pragma unroll
    for (int i = tid; i < 2048; i += 256) {
        int r = i >> 6, k4 = (i & 63) << 2;
        *(float4*)&xs[r*260 + k4] = *(const float4*)&x[(row0 + r)*CC + k4];
    }
    __syncthreads();

    const int colg = tid & 31, rowg = tid >> 5;
    const int c0 = colg * 8, r0 = rowg * 4;

    float acc[4][8];
    #pragma unroll
    for (int r=0;r<4;r++)
        #pragma unroll
        for (int j=0;j<8;j++) acc[r][j] = 0.f;

    for (int k = 0; k < CC; k += 4) {
        float4 xv[4];
        #pragma unroll
        for (int r=0;r<4;r++) xv[r] = *(const float4*)&xs[(r0+r)*260 + k];
        #pragma unroll
        for (int kk=0;kk<4;kk++){
            float4 w0 = *(const float4*)&W[(k+kk)*CC + c0];
            float4 w1 = *(const float4*)&W[(k+kk)*CC + c0 + 4];
            float wv[8] = {w0.x,w0.y,w0.z,w0.w,w1.x,w1.y,w1.z,w1.w};
            #pragma unroll
            for (int r=0;r<4;r++){
                float xr = (&xv[r].x)[kk];
                #pragma unroll
                for (int j=0;j<8;j++) acc[r][j] = fmaf(xr, wv[j], acc[r][j]);
            }
        }
    }

    #pragma unroll
    for (int r=0;r<4;r++){
        float o[8];
        #pragma unroll
        for (int j=0;j<8;j++){
            float z = 0.01f + acc[r][j] + b[c0+j];
            o[j] = softplus(z);
        }
        float* dst = &dt[(row0 + r0 + r)*CC + c0];
        *(float4*)&dst[0] = make_float4(o[0],o[1],o[2],o[3]);
        *(float4*)&dst[4] = make_float4(o[4],o[5],o[6],o[7]);
    }
}

// ---------------- Kernel B: boa = (1 + x@W_B + b_B)/A * log2e ; cm = x@W_C + b_C
__global__ __launch_bounds__(256) void k_bc(const float* __restrict__ x,
    const float* __restrict__ WB, const float* __restrict__ bB,
    const float* __restrict__ WC, const float* __restrict__ bC,
    const float* __restrict__ logA,
    float* __restrict__ boa, float* __restrict__ cm)
{
    __shared__ float xs[32*260];
    const int tid  = threadIdx.x;
    const int row0 = blockIdx.x * 32;
    #pragma unroll
    for (int i = tid; i < 2048; i += 256) {
        int r = i >> 6, k4 = (i & 63) << 2;
        *(float4*)&xs[r*260 + k4] = *(const float4*)&x[(row0 + r)*CC + k4];
    }
    __syncthreads();

    const int col = tid & 31, rowg = tid >> 5;
    const int r0 = rowg * 4;
    const int s = col & 15;
    const bool isB = (col < 16);
    const float* __restrict__ Wp = isB ? (WB + s) : (WC + s);

    float acc[4] = {0.f,0.f,0.f,0.f};
    for (int k = 0; k < CC; k += 4) {
        float4 xv[4];
        #pragma unroll
        for (int r=0;r<4;r++) xv[r] = *(const float4*)&xs[(r0+r)*260 + k];
        #pragma unroll
        for (int kk=0;kk<4;kk++){
            float w = Wp[(k+kk)*SS];
            #pragma unroll
            for (int r=0;r<4;r++) acc[r] = fmaf((&xv[r].x)[kk], w, acc[r]);
        }
    }

    if (isB) {
        float A = -fexp2(logA[s] * LOG2E);   // A = -exp(logA)
        float scale = LOG2E / A;
        #pragma unroll
        for (int r=0;r<4;r++)
            boa[(row0+r0+r)*SS + s] = (1.f + acc[r] + bB[s]) * scale;
    } else {
        #pragma unroll
        for (int r=0;r<4;r++)
            cm[(row0+r0+r)*SS + s] = acc[r] + bC[s];
    }
}

// ---------------- Kernel C: per-chunk aggregates (prod a, local h end) -------
__global__ __launch_bounds__(256) void k_scan1(const float* __restrict__ dt,
    const float* __restrict__ x, const float* __restrict__ boa,
    const float* __restrict__ logA,
    float* __restrict__ Aprod, float* __restrict__ Hloc)
{
    const int c = threadIdx.x;
    const int g = blockIdx.x;

    float Al2[SS];
    #pragma unroll
    for (int s=0;s<SS;s++) Al2[s] = -fexp2(logA[s]*LOG2E) * LOG2E; // A*log2e

    float Ap[SS], h[SS];
    #pragma unroll
    for (int s=0;s<SS;s++){ Ap[s]=1.f; h[s]=0.f; }

    int row = g*TT;
    float dtc = dt[row*CC + c];
    float xc  = x[row*CC + c];
    float bo[SS]; load16(bo, &boa[row*SS]);

    #pragma unroll 1
    for (int t=0;t<TT;t++){
        int nrow = row + 1; if (nrow >= LL) nrow = LL-1;
        float dtn = dt[nrow*CC + c];
        float xn  = x[nrow*CC + c];
        float bon[SS]; load16(bon, &boa[nrow*SS]);

        #pragma unroll
        for (int s=0;s<SS;s++){
            float a = fexp2(dtc * Al2[s]);                       // exp(dt*A)
            float u = fexp2(fmaf(a, bo[s], -bo[s])) * xc;        // exp((a-1)*B/A)*x
            h[s] = fmaf(a, h[s], u);
            Ap[s] *= a;
        }
        dtc = dtn; xc = xn;
        #pragma unroll
        for (int s=0;s<SS;s++) bo[s] = bon[s];
        row = nrow;
    }

    const int base = (g*CC + c)*SS;
    float tA[SS], tH[SS];
    #pragma unroll
    for (int s=0;s<SS;s++){ tA[s]=Ap[s]; tH[s]=h[s]; }
    *(float4*)&Aprod[base+0]  = make_float4(tA[0],tA[1],tA[2],tA[3]);
    *(float4*)&Aprod[base+4]  = make_float4(tA[4],tA[5],tA[6],tA[7]);
    *(float4*)&Aprod[base+8]  = make_float4(tA[8],tA[9],tA[10],tA[11]);
    *(float4*)&Aprod[base+12] = make_float4(tA[12],tA[13],tA[14],tA[15]);
    *(float4*)&Hloc[base+0]   = make_float4(tH[0],tH[1],tH[2],tH[3]);
    *(float4*)&Hloc[base+4]   = make_float4(tH[4],tH[5],tH[6],tH[7]);
    *(float4*)&Hloc[base+8]   = make_float4(tH[8],tH[9],tH[10],tH[11]);
    *(float4*)&Hloc[base+12]  = make_float4(tH[12],tH[13],tH[14],tH[15]);
}

// ---------------- Kernel D: serial carry scan across chunks ------------------
__global__ __launch_bounds__(256) void k_carry(const float* __restrict__ Ap,
    const float* __restrict__ Hl, float* __restrict__ Cr)
{
    const int j = blockIdx.x*256 + threadIdx.x;   // 0..4095 = c*16+s
    float h = 0.f;
    #pragma unroll 4
    for (int g=0; g<GG; ++g){
        Cr[g*(CC*SS) + j] = h;
        h = fmaf(Ap[g*(CC*SS) + j], h, Hl[g*(CC*SS) + j]);
    }
}

// ---------------- Kernel E: recompute + apply carry + contract to y ----------
__global__ __launch_bounds__(256) void k_scan2(const float* __restrict__ dt,
    const float* __restrict__ x, const float* __restrict__ boa,
    const float* __restrict__ cmat, const float* __restrict__ logA,
    const float* __restrict__ Cr, float* __restrict__ y)
{
    const int c = threadIdx.x;
    const int g = blockIdx.x;

    float Al2[SS];
    #pragma unroll
    for (int s=0;s<SS;s++) Al2[s] = -fexp2(logA[s]*LOG2E) * LOG2E;

    float h[SS];
    load16(h, &Cr[(g*CC + c)*SS]);

    int row = g*TT;
    float dtc = dt[row*CC + c];
    float xc  = x[row*CC + c];
    float bo[SS]; load16(bo, &boa[row*SS]);
    float cm[SS]; load16(cm, &cmat[row*SS]);

    #pragma unroll 1
    for (int t=0;t<TT;t++){
        int nrow = row + 1; if (nrow >= LL) nrow = LL-1;
        float dtn = dt[nrow*CC + c];
        float xn  = x[nrow*CC + c];
        float bon[SS]; load16(bon, &boa[nrow*SS]);
        float cmn[SS]; load16(cmn, &cmat[nrow*SS]);

        float yv = 0.f;
        #pragma unroll
        for (int s=0;s<SS;s++){
            float a = fexp2(dtc * Al2[s]);
            float u = fexp2(fmaf(a, bo[s], -bo[s])) * xc;
            h[s] = fmaf(a, h[s], u);
            yv = fmaf(cm[s], h[s], yv);
        }
        y[row*CC + c] = yv;

        dtc = dtn; xc = xn;
        #pragma unroll
        for (int s=0;s<SS;s++){ bo[s]=bon[s]; cm[s]=cmn[s]; }
        row = nrow;
    }
}

extern "C" void kernel_launch(void* const* d_in, const int* in_sizes, int n_in,
                              void* d_out, int out_size, void* d_ws, size_t ws_size,
                              hipStream_t stream) {
    const float* x    = (const float*)d_in[0];
    const float* logA = (const float*)d_in[1];
    const float* W_dt = (const float*)d_in[2];
    const float* b_dt = (const float*)d_in[3];
    const float* W_B  = (const float*)d_in[4];
    const float* b_B  = (const float*)d_in[5];
    const float* W_C  = (const float*)d_in[6];
    const float* b_C  = (const float*)d_in[7];
    float* y  = (float*)d_out;
    float* ws = (float*)d_ws;

    float* dt  = ws;                     // L*C      = 2,097,152
    float* boa = dt  + LL*CC;            // L*S      =   131,072
    float* cm  = boa + LL*SS;            // L*S      =   131,072
    float* Ap  = cm  + LL*SS;            // G*C*S    = 1,048,576
    float* Hl  = Ap  + GG*CC*SS;         // G*C*S
    float* Cr  = Hl  + GG*CC*SS;         // G*C*S    (total ~21 MB)

    hipLaunchKernelGGL(k_dt,    dim3(LL/32), dim3(256), 0, stream, x, W_dt, b_dt, dt);
    hipLaunchKernelGGL(k_bc,    dim3(LL/32), dim3(256), 0, stream, x, W_B, b_B, W_C, b_C, logA, boa, cm);
    hipLaunchKernelGGL(k_scan1, dim3(GG),    dim3(256), 0, stream, dt, x, boa, logA, Ap, Hl);
    hipLaunchKernelGGL(k_carry, dim3(CC*SS/256), dim3(256), 0, stream, Ap, Hl, Cr);
    hipLaunchKernelGGL(k_scan2, dim3(GG),    dim3(256), 0, stream, dt, x, boa, cm, logA, Cr, y);
}

// Round 2
// 156.404 us; speedup vs baseline: 1.1578x; 1.1578x over previous
//
#include <hip/hip_runtime.h>
#include <math.h>

#define LL 8192
#define CC 256
#define SS 16

#define LOG2E 1.4426950408889634f
#define LN2   0.6931471805599453f

__device__ __forceinline__ float fexp2(float v){ return __builtin_amdgcn_exp2f(v); }
__device__ __forceinline__ float flog2v(float v){ return __builtin_amdgcn_logf(v); }

// softplus(z) = max(z,0) + ln2 * log2(1 + 2^(-|z|*log2e))
__device__ __forceinline__ float softplus(float z){
    float t = fexp2(-fabsf(z) * LOG2E);
    return fmaxf(z, 0.f) + LN2 * flog2v(1.f + t);
}

__device__ __forceinline__ void load16(float* d, const float* __restrict__ p){
    *(float4*)&d[0]  = *(const float4*)&p[0];
    *(float4*)&d[4]  = *(const float4*)&p[4];
    *(float4*)&d[8]  = *(const float4*)&p[8];
    *(float4*)&d[12] = *(const float4*)&p[12];
}

// ============ k_proj: fused GEMM producing dt (softplus), boa, cm ============
// Logical output: (L=8192) x (320 cols): [0,256) = dt, [256,272) = boa,
// [272,288) = cm, [288,320) = discard.  Tiles: 64 rows x 64 cols, BK=32.
// colTile 0..3 -> dt; colTile 4 -> mixed boa/cm/pad.
#define BM 64
#define BN 64
#define BK 32
#define XSTR 68   // xs stride: keeps 16B alignment for b128 reads, breaks bank stride

__global__ __launch_bounds__(256) void k_proj(
    const float* __restrict__ x,
    const float* __restrict__ Wdt, const float* __restrict__ bdt,
    const float* __restrict__ WB,  const float* __restrict__ bB,
    const float* __restrict__ WC,  const float* __restrict__ bC,
    const float* __restrict__ logA,
    float* __restrict__ dt, float* __restrict__ boa, float* __restrict__ cm)
{
    __shared__ float xs[BK*XSTR];   // [k][m] transposed x tile
    __shared__ float wsd[BK*BN];    // [k][n]

    const int tid     = threadIdx.x;
    const int colTile = blockIdx.x;      // 0..4
    const int rowTile = blockIdx.y;      // 0..127
    const int row0    = rowTile * BM;
    const int n0      = colTile * BN;

    // staging index maps
    const int sr  = tid >> 3;            // 0..31 (x row within half-tile)
    const int sk4 = (tid & 7) * 4;       // 0..28 (k offset, x)
    const int wk  = tid >> 4;            // 0..15 (k within half, W)
    const int wn4 = (tid & 15) * 4;      // 0..60 (n offset, W)

    float acc[4][4];
    #pragma unroll
    for (int r=0;r<4;r++)
        #pragma unroll
        for (int j=0;j<4;j++) acc[r][j] = 0.f;

    const int tn = tid & 15, tm = tid >> 4;

    for (int k0 = 0; k0 < CC; k0 += BK) {
        // ---- stage x tile (transposed) ----
        #pragma unroll
        for (int h = 0; h < 2; h++) {
            int r = sr + h*32;
            float4 v = *(const float4*)&x[(size_t)(row0 + r)*CC + k0 + sk4];
            xs[(sk4+0)*XSTR + r] = v.x;
            xs[(sk4+1)*XSTR + r] = v.y;
            xs[(sk4+2)*XSTR + r] = v.z;
            xs[(sk4+3)*XSTR + r] = v.w;
        }
        // ---- stage W tile ----
        #pragma unroll
        for (int h = 0; h < 2; h++) {
            int k = k0 + wk + h*16;
            float4 w;
            if (colTile < 4) {
                w = *(const float4*)&Wdt[(size_t)k*CC + n0 + wn4];
            } else {
                if (wn4 < 16)      w = *(const float4*)&WB[(size_t)k*SS + wn4];
                else if (wn4 < 32) w = *(const float4*)&WC[(size_t)k*SS + (wn4-16)];
                else               w = make_float4(0.f,0.f,0.f,0.f);
            }
            *(float4*)&wsd[(wk + h*16)*BN + wn4] = w;
        }
        __syncthreads();

        #pragma unroll
        for (int kk = 0; kk < BK; kk++) {
            float4 av = *(const float4*)&xs[kk*XSTR + tm*4];
            float4 bv = *(const float4*)&wsd[kk*BN  + tn*4];
            const float* ap = &av.x; const float* bp = &bv.x;
            #pragma unroll
            for (int r=0;r<4;r++)
                #pragma unroll
                for (int j=0;j<4;j++)
                    acc[r][j] = fmaf(ap[r], bp[j], acc[r][j]);
        }
        __syncthreads();
    }

    // ---- epilogue ----
    const int m0 = row0 + tm*4;
    if (colTile < 4) {
        const int cg = n0 + tn*4;
        float4 bb = *(const float4*)&bdt[cg];
        const float* bbp = &bb.x;
        #pragma unroll
        for (int r=0;r<4;r++){
            float o[4];
            #pragma unroll
            for (int j=0;j<4;j++)
                o[j] = softplus(0.01f + acc[r][j] + bbp[j]);
            *(float4*)&dt[(size_t)(m0+r)*CC + cg] = make_float4(o[0],o[1],o[2],o[3]);
        }
    } else if (tn < 4) {               // boa cols: s = tn*4 .. +3
        const int s4 = tn*4;
        float sc[4], bv[4];
        #pragma unroll
        for (int j=0;j<4;j++){
            float A = -fexp2(logA[s4+j] * LOG2E);
            sc[j] = LOG2E / A;
            bv[j] = bB[s4+j];
        }
        #pragma unroll
        for (int r=0;r<4;r++){
            float o[4];
            #pragma unroll
            for (int j=0;j<4;j++)
                o[j] = (1.f + acc[r][j] + bv[j]) * sc[j];
            *(float4*)&boa[(size_t)(m0+r)*SS + s4] = make_float4(o[0],o[1],o[2],o[3]);
        }
    } else if (tn < 8) {               // cm cols: s = tn*4-16 .. +3
        const int s4 = tn*4 - 16;
        float bv[4];
        #pragma unroll
        for (int j=0;j<4;j++) bv[j] = bC[s4+j];
        #pragma unroll
        for (int r=0;r<4;r++){
            float o[4];
            #pragma unroll
            for (int j=0;j<4;j++)
                o[j] = acc[r][j] + bv[j];
            *(float4*)&cm[(size_t)(m0+r)*SS + s4] = make_float4(o[0],o[1],o[2],o[3]);
        }
    }
}

// ============ k_scan1: per-chunk aggregates (prod a, local h end) ============
__global__ __launch_bounds__(256) void k_scan1(const float* __restrict__ dt,
    const float* __restrict__ x, const float* __restrict__ boa,
    const float* __restrict__ logA,
    float* __restrict__ Aprod, float* __restrict__ Hloc, int TT)
{
    const int c = threadIdx.x;
    const int g = blockIdx.x;

    float Al2[SS];
    #pragma unroll
    for (int s=0;s<SS;s++) Al2[s] = -fexp2(logA[s]*LOG2E) * LOG2E; // A*log2e

    float Ap[SS], h[SS];
    #pragma unroll
    for (int s=0;s<SS;s++){ Ap[s]=1.f; h[s]=0.f; }

    int row = g*TT;
    float dtc = dt[(size_t)row*CC + c];
    float xc  = x[(size_t)row*CC + c];
    float bo[SS]; load16(bo, &boa[(size_t)row*SS]);

    #pragma unroll 1
    for (int t=0;t<TT;t++){
        int nrow = row + 1; if (nrow >= LL) nrow = LL-1;
        float dtn = dt[(size_t)nrow*CC + c];
        float xn  = x[(size_t)nrow*CC + c];
        float bon[SS]; load16(bon, &boa[(size_t)nrow*SS]);

        #pragma unroll
        for (int s=0;s<SS;s++){
            float a = fexp2(dtc * Al2[s]);                       // exp(dt*A)
            float u = fexp2(fmaf(a, bo[s], -bo[s])) * xc;        // exp((a-1)*B/A)*x
            h[s] = fmaf(a, h[s], u);
            Ap[s] *= a;
        }
        dtc = dtn; xc = xn;
        #pragma unroll
        for (int s=0;s<SS;s++) bo[s] = bon[s];
        row = nrow;
    }

    const size_t base = ((size_t)g*CC + c)*SS;
    *(float4*)&Aprod[base+0]  = make_float4(Ap[0],Ap[1],Ap[2],Ap[3]);
    *(float4*)&Aprod[base+4]  = make_float4(Ap[4],Ap[5],Ap[6],Ap[7]);
    *(float4*)&Aprod[base+8]  = make_float4(Ap[8],Ap[9],Ap[10],Ap[11]);
    *(float4*)&Aprod[base+12] = make_float4(Ap[12],Ap[13],Ap[14],Ap[15]);
    *(float4*)&Hloc[base+0]   = make_float4(h[0],h[1],h[2],h[3]);
    *(float4*)&Hloc[base+4]   = make_float4(h[4],h[5],h[6],h[7]);
    *(float4*)&Hloc[base+8]   = make_float4(h[8],h[9],h[10],h[11]);
    *(float4*)&Hloc[base+12]  = make_float4(h[12],h[13],h[14],h[15]);
}

// ============ k_carry: serial scan across chunks, 16-deep load batching ======
__global__ __launch_bounds__(256) void k_carry(const float* __restrict__ Ap,
    const float* __restrict__ Hl, float* __restrict__ Cr, int GG)
{
    const int j = blockIdx.x*256 + threadIdx.x;   // 0..4095 = c*16+s
    const int NJ = CC*SS;
    float h = 0.f;
    for (int g0 = 0; g0 < GG; g0 += 16) {
        float a[16], u[16];
        #pragma unroll
        for (int i=0;i<16;i++){
            a[i] = Ap[(size_t)(g0+i)*NJ + j];
            u[i] = Hl[(size_t)(g0+i)*NJ + j];
        }
        #pragma unroll
        for (int i=0;i<16;i++){
            Cr[(size_t)(g0+i)*NJ + j] = h;
            h = fmaf(a[i], h, u[i]);
        }
    }
}

// ============ k_scan2: recompute + apply carry + contract to y ===============
__global__ __launch_bounds__(256) void k_scan2(const float* __restrict__ dt,
    const float* __restrict__ x, const float* __restrict__ boa,
    const float* __restrict__ cmat, const float* __restrict__ logA,
    const float* __restrict__ Cr, float* __restrict__ y, int TT)
{
    const int c = threadIdx.x;
    const int g = blockIdx.x;

    float Al2[SS];
    #pragma unroll
    for (int s=0;s<SS;s++) Al2[s] = -fexp2(logA[s]*LOG2E) * LOG2E;

    float h[SS];
    load16(h, &Cr[((size_t)g*CC + c)*SS]);

    int row = g*TT;
    float dtc = dt[(size_t)row*CC + c];
    float xc  = x[(size_t)row*CC + c];
    float bo[SS]; load16(bo, &boa[(size_t)row*SS]);
    float cm[SS]; load16(cm, &cmat[(size_t)row*SS]);

    #pragma unroll 1
    for (int t=0;t<TT;t++){
        int nrow = row + 1; if (nrow >= LL) nrow = LL-1;
        float dtn = dt[(size_t)nrow*CC + c];
        float xn  = x[(size_t)nrow*CC + c];
        float bon[SS]; load16(bon, &boa[(size_t)nrow*SS]);
        float cmn[SS]; load16(cmn, &cmat[(size_t)nrow*SS]);

        float yv = 0.f;
        #pragma unroll
        for (int s=0;s<SS;s++){
            float a = fexp2(dtc * Al2[s]);
            float u = fexp2(fmaf(a, bo[s], -bo[s])) * xc;
            h[s] = fmaf(a, h[s], u);
            yv = fmaf(cm[s], h[s], yv);
        }
        y[(size_t)row*CC + c] = yv;

        dtc = dtn; xc = xn;
        #pragma unroll
        for (int s=0;s<SS;s++){ bo[s]=bon[s]; cm[s]=cmn[s]; }
        row = nrow;
    }
}

extern "C" void kernel_launch(void* const* d_in, const int* in_sizes, int n_in,
                              void* d_out, int out_size, void* d_ws, size_t ws_size,
                              hipStream_t stream) {
    const float* x    = (const float*)d_in[0];
    const float* logA = (const float*)d_in[1];
    const float* W_dt = (const float*)d_in[2];
    const float* b_dt = (const float*)d_in[3];
    const float* W_B  = (const float*)d_in[4];
    const float* b_B  = (const float*)d_in[5];
    const float* W_C  = (const float*)d_in[6];
    const float* b_C  = (const float*)d_in[7];
    float* y  = (float*)d_out;
    float* ws = (float*)d_ws;

    // choose chunk count by workspace size
    size_t need512 = ((size_t)LL*CC + 2ull*LL*SS + 3ull*512*CC*SS) * 4ull;
    const int GG = (ws_size >= need512) ? 512 : 256;
    const int TT = LL / GG;

    float* dt  = ws;                         // L*C
    float* boa = dt  + (size_t)LL*CC;        // L*S
    float* cmv = boa + (size_t)LL*SS;        // L*S
    float* Ap  = cmv + (size_t)LL*SS;        // GG*C*S
    float* Hl  = Ap  + (size_t)GG*CC*SS;     // GG*C*S
    float* Cr  = Hl  + (size_t)GG*CC*SS;     // GG*C*S

    hipLaunchKernelGGL(k_proj,  dim3(5,128), dim3(256), 0, stream,
                       x, W_dt, b_dt, W_B, b_B, W_C, b_C, logA, dt, boa, cmv);
    hipLaunchKernelGGL(k_scan1, dim3(GG),    dim3(256), 0, stream,
                       dt, x, boa, logA, Ap, Hl, TT);
    hipLaunchKernelGGL(k_carry, dim3(CC*SS/256), dim3(256), 0, stream, Ap, Hl, Cr, GG);
    hipLaunchKernelGGL(k_scan2, dim3(GG),    dim3(256), 0, stream,
                       dt, x, boa, cmv, logA, Cr, y, TT);
}